// Round 2
// 400.380 us; speedup vs baseline: 1.0231x; 1.0231x over previous
//
#include <hip/hip_runtime.h>
#include <stdint.h>

typedef __attribute__((ext_vector_type(4))) int int4v;
typedef __attribute__((ext_vector_type(16))) int int16v;
typedef __attribute__((ext_vector_type(4))) uint32_t uint4v;

#define M_DIM 8192
#define N_DIM 4096
#define K_DIM 4096

// K-permuted layout: within each 64-byte K chunk, stored byte p holds
// original k = (p>>2) + 16*(p&3). Applied identically to A and B => MFMA
// dot products unchanged. GEMM XOR-swizzles 16-B chunks within each 128-B
// LDS row (slot = chunk ^ (row&7)); swizzle applied in the global source
// address at staging and inverted at fragment-read time.

// ---------------- pack x: int32 -> int8, K-permuted ----------------
__global__ void pack_a_perm(const int* __restrict__ x, uint4v* __restrict__ a8) {
    const int g = blockIdx.x * blockDim.x + threadIdx.x;  // global 16-B word index
    const int w0 = (g & 3) * 4;                           // word slot within chunk
    const int chunk = g >> 2;                             // 64-element k chunk
    const int* base = x + (size_t)chunk * 64;
    int4v L[4];
#pragma unroll
    for (int j = 0; j < 4; ++j) L[j] = *(const int4v*)(base + j * 16 + w0);
    uint4v outv;
#pragma unroll
    for (int wi = 0; wi < 4; ++wi) {
        outv[wi] = (uint32_t)(L[0][wi] & 0xff) | ((uint32_t)(L[1][wi] & 0xff) << 8) |
                   ((uint32_t)(L[2][wi] & 0xff) << 16) | ((uint32_t)(L[3][wi] & 0xff) << 24);
    }
    a8[g] = outv;
}

// ------- transpose+pack weight: [K][N] int32 -> Bt[N][K-permuted] int8 -------
__global__ void transpose_b_perm(const int* __restrict__ w, int8_t* __restrict__ bt) {
    const int t = threadIdx.x;
    const int kt = blockIdx.y * 64;
    const int n0 = blockIdx.x * 64;
    const int c4 = t & 3;
    const int n = t >> 2;
    const int w0 = c4 * 4;
    const int* col = w + (size_t)kt * N_DIM + n0 + n;
    uint4v outv;
#pragma unroll
    for (int wi = 0; wi < 4; ++wi) {
        uint32_t p = 0;
#pragma unroll
        for (int j = 0; j < 4; ++j) {
            uint32_t b = (uint32_t)(col[(size_t)(w0 + wi + 16 * j) * N_DIM] & 0xff);
            p |= b << (8 * j);
        }
        outv[wi] = p;
    }
    *(uint4v*)&bt[(size_t)(n0 + n) * K_DIM + kt + w0 * 4] = outv;
}

// ---------------- GEMM: 256x256 tile, BK=128, 8-phase pipeline ----------------
__device__ inline void async16(const void* g, void* l) {
    __builtin_amdgcn_global_load_lds(
        (const __attribute__((address_space(1))) uint32_t*)g,
        (__attribute__((address_space(3))) uint32_t*)l, 16, 0, 0);
}

__global__ void __launch_bounds__(512, 2)
gemm_kernel(const int8_t* __restrict__ A, const int8_t* __restrict__ Bt,
            const float* __restrict__ pa, const float* __restrict__ pb,
            int* __restrict__ out) {
    // LDS: buf0: A@0 (32K), B@32768 (32K); buf1: A@65536, B@98304. 128 KiB.
    __shared__ int8_t smem[131072];

    const int t = threadIdx.x;
    const int lane = t & 63;
    const int wave = t >> 6;

    // XCD-aware bijective swizzle (nwg = 512, divisible by 8)
    int wg = (int)blockIdx.x;
    wg = (wg & 7) * (512 / 8) + (wg >> 3);
    const int bx = wg & 15;         // N / 256 = 16
    const int by = wg >> 4;         // M / 256 = 32
    const int m0 = by * 256;
    const int n0 = bx * 256;

    const int wm = (wave >> 2) * 128;   // 2 waves along M
    const int wn = (wave & 3) * 64;     // 4 waves along N
    const float scale = pa[0] * pb[0];

    // ---- staging constants (linear LDS dest; swizzle folded into global src) ----
    const int srow8 = wave * 8 + (lane >> 3);               // row within 64-row chunk
    const int gcol = ((lane & 7) ^ (srow8 & 7)) * 16;       // pre-swizzled source chunk
    const int8_t* pA = A + (size_t)(m0 + srow8) * K_DIM + gcol;
    const int8_t* pB = Bt + (size_t)(n0 + srow8) * K_DIM + gcol;

    // ---- fragment-read constants ----
    const int ra0 = wm + (lane & 31);
    const int rb0 = wn + (lane & 31);
    const int rx7 = lane & 7;     // == row&7 for every fragment row this lane reads
    const int hl = lane >> 5;     // k-half within 32-B MFMA window

    int16v acc[4][2];
#pragma unroll
    for (int mi = 0; mi < 4; ++mi)
#pragma unroll
        for (int j = 0; j < 2; ++j)
#pragma unroll
            for (int r = 0; r < 16; ++r) acc[mi][j][r] = 0;

    int4v af[2][2], bf[2][2];

#define STAGE_A(c, kt, buf) async16(pA + (size_t)(c) * 64 * K_DIM + (kt), \
                                    smem + (buf) * 65536 + ((c) * 64 + wave * 8) * 128)
#define STAGE_B(c, kt, buf) async16(pB + (size_t)(c) * 64 * K_DIM + (kt), \
                                    smem + (buf) * 65536 + 32768 + ((c) * 64 + wave * 8) * 128)

#define PH_READ(BUF, KH, MH, READB) do {                                          \
        const int abase_ = (BUF) * 65536;                                         \
        if (READB) {                                                              \
            _Pragma("unroll")                                                     \
            for (int ks = 0; ks < 2; ++ks) {                                      \
                const int off_ = ((((KH) * 2 + ks) * 2 + hl) ^ rx7) << 4;         \
                bf[0][ks] = *(const int4v*)&smem[abase_ + 32768 + rb0 * 128 + off_]; \
                bf[1][ks] = *(const int4v*)&smem[abase_ + 32768 + (rb0 + 32) * 128 + off_]; \
            }                                                                     \
        }                                                                         \
        _Pragma("unroll")                                                         \
        for (int ks = 0; ks < 2; ++ks) {                                          \
            const int off_ = ((((KH) * 2 + ks) * 2 + hl) ^ rx7) << 4;             \
            af[0][ks] = *(const int4v*)&smem[abase_ + (ra0 + (MH) * 64) * 128 + off_]; \
            af[1][ks] = *(const int4v*)&smem[abase_ + (ra0 + (MH) * 64 + 32) * 128 + off_]; \
        }                                                                         \
    } while (0)

#define PH_TAIL(MH, ENDWAIT) do {                                                 \
        __builtin_amdgcn_sched_barrier(0);                                        \
        __builtin_amdgcn_s_barrier();                                             \
        asm volatile("s_waitcnt lgkmcnt(0)");                                     \
        __builtin_amdgcn_sched_barrier(0);                                        \
        __builtin_amdgcn_s_setprio(1);                                            \
        _Pragma("unroll")                                                         \
        for (int ks = 0; ks < 2; ++ks)                                            \
            _Pragma("unroll")                                                     \
            for (int i = 0; i < 2; ++i)                                           \
                _Pragma("unroll")                                                 \
                for (int j = 0; j < 2; ++j)                                       \
                    acc[(MH) * 2 + i][j] = __builtin_amdgcn_mfma_i32_32x32x32_i8( \
                        af[i][ks], bf[j][ks], acc[(MH) * 2 + i][j], 0, 0, 0);     \
        __builtin_amdgcn_s_setprio(0);                                            \
        if (ENDWAIT) asm volatile("s_waitcnt vmcnt(2)");                          \
        __builtin_amdgcn_s_barrier();                                             \
    } while (0)

    // prologue: stage tile 0 into buf0; order a0,a2,b0,b1,b2,b3,a1,a3
    STAGE_A(0, 0, 0); STAGE_A(2, 0, 0);
    STAGE_B(0, 0, 0); STAGE_B(1, 0, 0);
    STAGE_B(2, 0, 0); STAGE_B(3, 0, 0);
    STAGE_A(1, 0, 0); STAGE_A(3, 0, 0);
    asm volatile("s_waitcnt vmcnt(2)");   // first 6 chunks landed (a0,a2,b0..b3)
    __builtin_amdgcn_s_barrier();

#pragma unroll 1
    for (int t2 = 0; t2 < 32; t2 += 2) {
        const int kt1 = t2 * 128 + 128;             // tile 2t+1 -> buf1 (always valid)
        // tile 2t+2 -> buf0. On the final iteration this wraps to kt=0: a dead
        // restage into the no-longer-read buf0. Keeping the stage ALWAYS issued
        // keeps the vmcnt ledger identical in every iteration -- P5's vmcnt(2)
        // must retire tile kt1's a1,a3 before P6 reads them (the prior guarded
        // version skipped these issues on the last tile => race, absmax 78).
        const int kt2 = (t2 * 128 + 256) & (K_DIM - 1);
        // ---- P1: buf0 (k-half0, m-half0); stage a0,a2 of tile 2t+1
        PH_READ(0, 0, 0, 1);
        STAGE_A(0, kt1, 1); STAGE_A(2, kt1, 1);
        PH_TAIL(0, 1);
        // ---- P2: (k0,m1), reuse bf; stage b0,b1
        PH_READ(0, 0, 1, 0);
        STAGE_B(0, kt1, 1); STAGE_B(1, kt1, 1);
        PH_TAIL(1, 0);
        // ---- P3: (k1,m0); stage b2,b3
        PH_READ(0, 1, 0, 1);
        STAGE_B(2, kt1, 1); STAGE_B(3, kt1, 1);
        PH_TAIL(0, 0);
        // ---- P4: (k1,m1), reuse bf; stage a1,a3; wait -> P5 can read buf1
        PH_READ(0, 1, 1, 0);
        STAGE_A(1, kt1, 1); STAGE_A(3, kt1, 1);
        PH_TAIL(1, 1);
        // ---- P5: buf1 (k0,m0); stage a0,a2 of tile 2t+2; wait -> P6 needs a1,a3
        PH_READ(1, 0, 0, 1);
        STAGE_A(0, kt2, 0); STAGE_A(2, kt2, 0);
        PH_TAIL(0, 1);
        // ---- P6: (k0,m1); stage b0,b1
        PH_READ(1, 0, 1, 0);
        STAGE_B(0, kt2, 0); STAGE_B(1, kt2, 0);
        PH_TAIL(1, 0);
        // ---- P7: (k1,m0); stage b2,b3
        PH_READ(1, 1, 0, 1);
        STAGE_B(2, kt2, 0); STAGE_B(3, kt2, 0);
        PH_TAIL(0, 0);
        // ---- P8: (k1,m1); stage a1,a3; wait -> next P1 can read buf0
        PH_READ(1, 1, 1, 0);
        STAGE_A(1, kt2, 0); STAGE_A(3, kt2, 0);
        PH_TAIL(1, 1);
    }

    // Drain all outstanding global_load_lds before the waves can end: an
    // in-flight LDS DMA outliving the workgroup can land in the LDS of the
    // next block scheduled on this CU.
    asm volatile("s_waitcnt vmcnt(0)");

    // ---- epilogue: dequant + saturate + store ----
    const int col = lane & 31;
    const int rbase = (lane >> 5) * 4;
#pragma unroll
    for (int mi = 0; mi < 4; ++mi)
#pragma unroll
        for (int j = 0; j < 2; ++j)
#pragma unroll
            for (int r = 0; r < 16; ++r) {
                const int rowf = rbase + (r & 3) + 8 * (r >> 2);
                float v = (float)acc[mi][j][r] * scale;
                v = rintf(v);
                v = fminf(127.f, fmaxf(-128.f, v));
                out[(size_t)(m0 + wm + mi * 32 + rowf) * N_DIM +
                    (n0 + wn + j * 32 + col)] = (int)v;
            }
#undef STAGE_A
#undef STAGE_B
#undef PH_READ
#undef PH_TAIL
}

extern "C" void kernel_launch(void* const* d_in, const int* in_sizes, int n_in,
                              void* d_out, int out_size, void* d_ws, size_t ws_size,
                              hipStream_t stream) {
    const int* x = (const int*)d_in[0];
    const int* w = (const int*)d_in[1];
    const float* pa = (const float*)d_in[2];
    const float* pb = (const float*)d_in[3];
    int* out = (int*)d_out;

    int8_t* a8 = (int8_t*)d_ws;                       // 32 MiB
    int8_t* bt8 = a8 + (size_t)M_DIM * K_DIM;         // 16 MiB

    const int nwords_a = M_DIM * K_DIM / 16;
    pack_a_perm<<<nwords_a / 256, 256, 0, stream>>>(x, (uint4v*)a8);
    transpose_b_perm<<<dim3(N_DIM / 64, K_DIM / 64), 256, 0, stream>>>(w, bt8);
    gemm_kernel<<<dim3(512), dim3(512), 0, stream>>>(a8, bt8, pa, pb, out);
}